// Round 5
// baseline (868.336 us; speedup 1.0000x reference)
//
#include <hip/hip_runtime.h>
#include <hip/hip_bf16.h>

// Problem constants (DeltaNet_6614249636545)
#define BB 2
#define TT 4096
#define HH 16
#define DKk 128
#define DVv 128
#define HIDD 2048
#define CC 64
#define NN 64          // TT / CC
#define GG 8           // dv 16-col windows in scan kernel
#define QSCALE 0.08838834764831845f  // 128^-0.5

static __device__ __forceinline__ unsigned short f2bf(float f) {
  unsigned u = __float_as_uint(f);
  u += 0x7fffu + ((u >> 16) & 1u);   // round-to-nearest-even
  return (unsigned short)(u >> 16);
}
static __device__ __forceinline__ float bf2f(unsigned short s) {
  return __uint_as_float(((unsigned)s) << 16);
}
static __device__ __forceinline__ unsigned packbf(float lo, float hi) {
  return (unsigned)f2bf(lo) | ((unsigned)f2bf(hi) << 16);
}

typedef short bf8 __attribute__((ext_vector_type(8)));
typedef float f4 __attribute__((ext_vector_type(4)));

// ---------------------------------------------------------------------------
// K0: transpose + bf16-cast projection weights: W[k][h] fp32 -> Wt[h][k] bf16
// ---------------------------------------------------------------------------
__global__ __launch_bounds__(256) void k0_wt(
    const float* __restrict__ Wb, const float* __restrict__ Wg,
    unsigned short* __restrict__ Wtb, unsigned short* __restrict__ Wtg) {
  int blk = blockIdx.x;
  const float* W = (blk < 8) ? Wb : Wg;
  unsigned short* Wt = (blk < 8) ? Wtb : Wtg;
  int k0 = (blk & 7) * 256;
  int tid = threadIdx.x;
  __shared__ unsigned short st[16][272];
  const float* p = W + (size_t)(k0 + tid) * HH;
#pragma unroll
  for (int h4 = 0; h4 < 4; h4++) {
    float4 x = *(const float4*)(p + h4 * 4);
    st[h4 * 4 + 0][tid] = f2bf(x.x);
    st[h4 * 4 + 1][tid] = f2bf(x.y);
    st[h4 * 4 + 2][tid] = f2bf(x.z);
    st[h4 * 4 + 3][tid] = f2bf(x.w);
  }
  __syncthreads();
  int h = tid >> 4, c = (tid & 15) << 4;
#pragma unroll
  for (int j = 0; j < 16; j++)
    Wt[(size_t)h * HIDD + k0 + c + j] = st[h][c + j];
}

// ---------------------------------------------------------------------------
// K0p: per-head transpose of o_proj_w: P[h][v][d] fp32 -> Ppt[h][d][v] bf16.
// ---------------------------------------------------------------------------
__global__ __launch_bounds__(256) void k0p_pt(
    const float* __restrict__ opw, unsigned short* __restrict__ Ppt) {
  int h = blockIdx.x;
  int tid = threadIdx.x;
  __shared__ unsigned short sp[128 * 132];
  const float* P = opw + (size_t)h * (DVv * DKk);
  for (int it = 0; it < 16; it++) {
    int idx = it * 256 + tid;            // 4096 float4 quads
    int vv = idx >> 5, d4 = (idx & 31) << 2;
    float4 x = *(const float4*)(P + vv * 128 + d4);
    sp[vv * 132 + d4 + 0] = f2bf(x.x);
    sp[vv * 132 + d4 + 1] = f2bf(x.y);
    sp[vv * 132 + d4 + 2] = f2bf(x.z);
    sp[vv * 132 + d4 + 3] = f2bf(x.w);
  }
  __syncthreads();
  unsigned short* dst = Ppt + (size_t)h * (DVv * DKk);
  for (int it = 0; it < 8; it++) {
    int idx = it * 256 + tid;            // 2048 groups of 8
    int d = idx >> 4, v8 = (idx & 15) << 3;
    unsigned short tmp[8];
#pragma unroll
    for (int j = 0; j < 8; j++) tmp[j] = sp[(v8 + j) * 132 + d];
    *(uint4*)&dst[d * 128 + v8] = *(uint4*)tmp;
  }
}

// ---------------------------------------------------------------------------
// K1 (MFMA): beta = sigmoid(hab @ Wb), graw = hg @ Wg as skinny GEMM.
// R9: additionally writes bt[b][h][T] (beta transposed, contiguous in t) so
// k4 can load per-row-tile beta as one float4.
// ---------------------------------------------------------------------------
__global__ __launch_bounds__(256) void k1_beta_g(
    const float* __restrict__ hab, const float* __restrict__ hg,
    const unsigned short* __restrict__ Wtb, const unsigned short* __restrict__ Wtg,
    float* __restrict__ beta, float* __restrict__ graw,
    float* __restrict__ bt) {
  int tile = blockIdx.x;               // 512 tiles of 16 tokens
  int tid = threadIdx.x;
  int w = tid >> 6, lane = tid & 63;
  int proj = w >> 1, ks = w & 1;
  int n16 = lane & 15, qd = lane >> 4;
  const float* hid = proj ? hg : hab;
  const unsigned short* Wt = proj ? Wtg : Wtb;
  size_t rowbase = (size_t)(tile * 16 + n16) * HIDD;
  int k0 = ks * 1024;

  f4 acc = {0.f, 0.f, 0.f, 0.f};
  for (int s = 0; s < 32; s++) {
    int kk = k0 + s * 32 + qd * 8;
    const float* hp = hid + rowbase + kk;
    float4 h0 = *(const float4*)hp;
    float4 h1 = *(const float4*)(hp + 4);
    bf8 a;
    a[0] = (short)f2bf(h0.x); a[1] = (short)f2bf(h0.y);
    a[2] = (short)f2bf(h0.z); a[3] = (short)f2bf(h0.w);
    a[4] = (short)f2bf(h1.x); a[5] = (short)f2bf(h1.y);
    a[6] = (short)f2bf(h1.z); a[7] = (short)f2bf(h1.w);
    bf8 b = *(const bf8*)&Wt[(size_t)n16 * HIDD + kk];
    acc = __builtin_amdgcn_mfma_f32_16x16x32_bf16(a, b, acc, 0, 0, 0);
  }

  __shared__ float red[2][16][17];
  if (ks == 1) {
#pragma unroll
    for (int r = 0; r < 4; r++) red[proj][qd * 4 + r][n16] = acc[r];
  }
  __syncthreads();
  if (ks == 0) {
#pragma unroll
    for (int r = 0; r < 4; r++) {
      float s = acc[r] + red[proj][qd * 4 + r][n16];
      int tg = tile * 16 + qd * 4 + r;        // global token index in [0, B*T)
      size_t t = (size_t)tg * HH + n16;
      if (proj == 0) {
        float bv = 1.f / (1.f + expf(-s));
        beta[t] = bv;
        int bb = tg >> 12;                    // / TT
        int ti = tg & (TT - 1);
        bt[((size_t)(bb * HH + n16)) * TT + ti] = bv;
      } else {
        graw[t] = s;
      }
    }
  }
}

// ---------------------------------------------------------------------------
// K2: l2norm(q)*scale -> qn (bf16), l2norm(k) -> kn (bf16)
// ---------------------------------------------------------------------------
__global__ __launch_bounds__(256) void k2_l2norm(
    const float* __restrict__ q, const float* __restrict__ k,
    unsigned short* __restrict__ qn, unsigned short* __restrict__ kn) {
  int lane = threadIdx.x & 63, wave = threadIdx.x >> 6;
  for (int u = 0; u < 2; u++) {
    int vec = blockIdx.x * 8 + wave * 2 + u;
    size_t off = (size_t)vec * 64 + lane;
    float2 q2 = ((const float2*)q)[off];
    float2 k2 = ((const float2*)k)[off];
    float sq = q2.x * q2.x + q2.y * q2.y;
    float sk = k2.x * k2.x + k2.y * k2.y;
#pragma unroll
    for (int m = 32; m; m >>= 1) { sq += __shfl_xor(sq, m); sk += __shfl_xor(sk, m); }
    float rq = rsqrtf(sq + 1e-6f) * QSCALE;
    float rk = rsqrtf(sk + 1e-6f);
    unsigned pq = (unsigned)f2bf(q2.x * rq) | ((unsigned)f2bf(q2.y * rq) << 16);
    unsigned pk = (unsigned)f2bf(k2.x * rk) | ((unsigned)f2bf(k2.y * rk) << 16);
    ((unsigned*)qn)[off] = pq;
    ((unsigned*)kn)[off] = pk;
  }
}

// ---------------------------------------------------------------------------
// K3 (MFMA): per chunk: attn = tril(q k^T), A = tril(k_beta k^T,-1),
//   T = (I+A)^{-1} via nilpotent doubling, then:
//     ATg = attn @ T   [64 x 64]
//     Ktg = k^T @ T    [128 x 64] (row-major in dk)
// ---------------------------------------------------------------------------
#define SW 72          // stride (shorts) of 64x64 bf16 mats
#define K3_M0R 8704
#define K3_M0T 13312
#define K3_M1R 17920
#define K3_M1T 22528
#define K3_TB  27136   // T^T (col-major shadow of T), bf16
#define K3_ARENA 31744 // 63488 B

__global__ __launch_bounds__(256) void k3_chunk(
    const unsigned short* __restrict__ qn, const unsigned short* __restrict__ kn,
    const float* __restrict__ beta,
    unsigned short* __restrict__ ATg, unsigned short* __restrict__ Ktg) {
  int cid = blockIdx.x;
  int n = cid & (NN - 1);
  int bh = cid / NN;
  int h = bh & (HH - 1);
  int b = bh / HH;
  int tid = threadIdx.x;
  int w = tid >> 6;
  int lane = tid & 63;
  int n16 = lane & 15;
  int qd = lane >> 4;
  int r0 = w * 16;

  __shared__ __align__(16) unsigned short arena[K3_ARENA];
  __shared__ float sb[CC];
  unsigned short* sk = arena;           // [c][dk] stride 136, LIVE throughout
  unsigned short* sq = arena + 8704;    // aliased by M buffers after attn

  int t0 = n * CC;
#pragma unroll
  for (int p = 0; p < 4; p++) {
    int id = p * 256 + tid, row = id >> 4, c8 = (id & 15) << 3;
    size_t g = ((size_t)((b * TT + t0 + row) * HH + h)) * DKk + c8;
    *(uint4*)&sk[row * 136 + c8] = *(const uint4*)(kn + g);
    *(uint4*)&sq[row * 136 + c8] = *(const uint4*)(qn + g);
  }
  if (tid < CC) sb[tid] = beta[(size_t)((b * TT + t0 + tid) * HH + h)];
  __syncthreads();

  // ---- attn = q k^T and raw kk = k k^T   (MFMA, K=128)
  f4 at[4], mk[4];
#pragma unroll
  for (int ct = 0; ct < 4; ct++) { at[ct] = (f4){0,0,0,0}; mk[ct] = (f4){0,0,0,0}; }
#pragma unroll
  for (int s = 0; s < 4; s++) {
    bf8 aq = *(const bf8*)&sq[(r0 + n16) * 136 + s * 32 + qd * 8];
    bf8 ak = *(const bf8*)&sk[(r0 + n16) * 136 + s * 32 + qd * 8];
#pragma unroll
    for (int ct = 0; ct < 4; ct++) {
      bf8 bk = *(const bf8*)&sk[(ct * 16 + n16) * 136 + s * 32 + qd * 8];
      at[ct] = __builtin_amdgcn_mfma_f32_16x16x32_bf16(aq, bk, at[ct], 0, 0, 0);
      mk[ct] = __builtin_amdgcn_mfma_f32_16x16x32_bf16(ak, bk, mk[ct], 0, 0, 0);
    }
  }

  f4 tf[4];
  float mpv[4][4];
#pragma unroll
  for (int ct = 0; ct < 4; ct++) {
#pragma unroll
    for (int r = 0; r < 4; r++) {
      int i = r0 + qd * 4 + r, j = ct * 16 + n16;
      at[ct][r] = (j <= i) ? at[ct][r] : 0.f;      // masked attn kept in regs
      float mp = (j < i) ? -sb[i] * mk[ct][r] : 0.f;
      mpv[ct][r] = mp;
      tf[ct][r] = (i == j) ? 1.f : mp;
    }
  }
  __syncthreads();   // reads of sq done; M region usable

#pragma unroll
  for (int ct = 0; ct < 4; ct++) {
#pragma unroll
    for (int r = 0; r < 4; r++) {
      int i = r0 + qd * 4 + r, j = ct * 16 + n16;
      unsigned short hm = f2bf(mpv[ct][r]);
      arena[K3_M0R + i * SW + j] = hm;
      arena[K3_M0T + j * SW + i] = hm;
      arena[K3_TB + j * SW + i] = f2bf(tf[ct][r]);
    }
  }
  __syncthreads();

  int p = 0;
  for (int it = 1; it <= 5; it++) {
    int mrp = p ? K3_M1R : K3_M0R, mtp = p ? K3_M1T : K3_M0T;
    int mrn = p ? K3_M0R : K3_M1R, mtn = p ? K3_M0T : K3_M1T;
    f4 nr[4];
#pragma unroll
    for (int ct = 0; ct < 4; ct++) nr[ct] = (f4){0,0,0,0};
#pragma unroll
    for (int s = 0; s < 2; s++) {
      bf8 a = *(const bf8*)&arena[mrp + (r0 + n16) * SW + s * 32 + qd * 8];
#pragma unroll
      for (int ct = 0; ct < 4; ct++) {
        bf8 bb = *(const bf8*)&arena[mtp + (ct * 16 + n16) * SW + s * 32 + qd * 8];
        nr[ct] = __builtin_amdgcn_mfma_f32_16x16x32_bf16(a, bb, nr[ct], 0, 0, 0);
      }
    }
#pragma unroll
    for (int ct = 0; ct < 4; ct++) {
#pragma unroll
      for (int r = 0; r < 4; r++) {
        int i = r0 + qd * 4 + r, j = ct * 16 + n16;
        unsigned short hm = f2bf(nr[ct][r]);
        arena[mrn + i * SW + j] = hm;
        arena[mtn + j * SW + i] = hm;
      }
    }
    __syncthreads();  // B1

    // phase B: Tf += N · T
#pragma unroll
    for (int s = 0; s < 2; s++) {
      bf8 a = *(const bf8*)&arena[mrn + (r0 + n16) * SW + s * 32 + qd * 8];
#pragma unroll
      for (int ct = 0; ct < 4; ct++) {
        bf8 bb = *(const bf8*)&arena[K3_TB + (ct * 16 + n16) * SW + s * 32 + qd * 8];
        tf[ct] = __builtin_amdgcn_mfma_f32_16x16x32_bf16(a, bb, tf[ct], 0, 0, 0);
      }
    }
    __syncthreads();  // B2

    if (it < 5) {
#pragma unroll
      for (int ct = 0; ct < 4; ct++) {
#pragma unroll
        for (int r = 0; r < 4; r++) {
          int i = r0 + qd * 4 + r, j = ct * 16 + n16;
          arena[K3_TB + j * SW + i] = f2bf(tf[ct][r]);
        }
      }
    }
    p = 1 - p;
  }

  // ---- post-loop: attn -> M0R (dead), FINAL T^T -> TB
#pragma unroll
  for (int ct = 0; ct < 4; ct++) {
#pragma unroll
    for (int r = 0; r < 4; r++) {
      int i = r0 + qd * 4 + r, j = ct * 16 + n16;
      arena[K3_M0R + i * SW + j] = f2bf(at[ct][r]);
      arena[K3_TB + j * SW + i] = f2bf(tf[ct][r]);
    }
  }
  __syncthreads();

  // ---- ATg = attn @ T
  {
    f4 ac[4];
#pragma unroll
    for (int ct = 0; ct < 4; ct++) ac[ct] = (f4){0,0,0,0};
#pragma unroll
    for (int s = 0; s < 2; s++) {
      bf8 a = *(const bf8*)&arena[K3_M0R + (r0 + n16) * SW + s * 32 + qd * 8];
#pragma unroll
      for (int ct = 0; ct < 4; ct++) {
        bf8 bb = *(const bf8*)&arena[K3_TB + (ct * 16 + n16) * SW + s * 32 + qd * 8];
        ac[ct] = __builtin_amdgcn_mfma_f32_16x16x32_bf16(a, bb, ac[ct], 0, 0, 0);
      }
    }
    size_t abase = (size_t)cid * (CC * CC);
#pragma unroll
    for (int ct = 0; ct < 4; ct++)
#pragma unroll
      for (int r = 0; r < 4; r++)
        ATg[abase + (r0 + qd * 4 + r) * CC + ct * 16 + n16] = f2bf(ac[ct][r]);
  }

  // ---- Ktg = k^T @ T   (wave w owns dk rows w*32..w*32+31)
  {
    size_t kbase = (size_t)cid * (DKk * CC);
#pragma unroll
    for (int t = 0; t < 2; t++) {
      int dkt = w * 32 + t * 16;
      f4 ac[4];
#pragma unroll
      for (int ct = 0; ct < 4; ct++) ac[ct] = (f4){0,0,0,0};
#pragma unroll
      for (int s = 0; s < 2; s++) {
        bf8 a;
#pragma unroll
        for (int jj = 0; jj < 8; jj++)
          a[jj] = (short)sk[(s * 32 + qd * 8 + jj) * 136 + dkt + n16];
#pragma unroll
        for (int ct = 0; ct < 4; ct++) {
          bf8 bb = *(const bf8*)&arena[K3_TB + (ct * 16 + n16) * SW + s * 32 + qd * 8];
          ac[ct] = __builtin_amdgcn_mfma_f32_16x16x32_bf16(a, bb, ac[ct], 0, 0, 0);
        }
      }
#pragma unroll
      for (int ct = 0; ct < 4; ct++)
#pragma unroll
        for (int r = 0; r < 4; r++)
          Ktg[kbase + (dkt + qd * 4 + r) * CC + ct * 16 + n16] = f2bf(ac[ct][r]);
    }
  }
}

// ---------------------------------------------------------------------------
// K4 (MFMA): sequential chunk scan, R9: ONE WAVE per window-scan, ZERO
// barriers, zero cross-wave traffic. 256 independent scans = grid 256 blocks
// of 64 threads (1 wave/CU). S held in registers (8 f4 C-tiles + 4 bf8
// B-frags). The two layout conversions (x C->B, S C->B) are wave-private LDS
// round-trips ordered by the in-order DS pipe (compiler lgkmcnt) -- no
// s_barrier anywhere. A-operands are per-lane 16B global loads (L2/L3
// resident, shared by the 8 windows of the same (b,h)).
// ---------------------------------------------------------------------------
__global__ __launch_bounds__(64, 1) void k4_scan(
    const unsigned short* __restrict__ qn, const unsigned short* __restrict__ kn,
    const float* __restrict__ v, const float* __restrict__ bt,
    const unsigned short* __restrict__ ATg, const unsigned short* __restrict__ Ktg,
    float* __restrict__ o) {
  int bi = blockIdx.x;                 // jg*32 + bh (same-bh blocks adjacent)
  int jg = bi >> 5;                    // 0..7
  int bh = bi & 31;
  int h = bh & (HH - 1);
  int b = bh >> 4;
  int lane = threadIdx.x;              // 0..63
  int n16 = lane & 15;
  int qd = lane >> 4;

  __shared__ __align__(16) unsigned short xb[16 * SW];     // 2304 B  x^T
  __shared__ __align__(16) unsigned short Sb[16 * 136];    // 4352 B  S^T

  f4 S[8];
#pragma unroll
  for (int i = 0; i < 8; i++) S[i] = (f4){0.f, 0.f, 0.f, 0.f};
  bf8 bS0 = {}, bS1 = {}, bS2 = {}, bS3 = {};   // S B-frags (zero initial)

  size_t bhN = (size_t)(b * HH + h) * NN;
  // per-lane base pointers
  const unsigned short* knb =
      kn + ((size_t)((b * TT + n16) * HH + h)) * DKk + qd * 8;
  const unsigned short* qnb =
      qn + ((size_t)((b * TT + n16) * HH + h)) * DKk + qd * 8;
  const unsigned short* atb = ATg + bhN * (CC * CC) + n16 * CC + qd * 8;
  const unsigned short* ktb = Ktg + bhN * (DKk * CC) + n16 * CC + qd * 8;
  const float* vbase =
      v + ((size_t)((b * TT + qd * 4) * HH + h)) * DVv + jg * 16 + n16;
  const float* btb = bt + (size_t)(b * HH + h) * TT + qd * 4;
  float* ob =
      o + ((size_t)((b * TT + qd * 4) * HH + h)) * DVv + jg * 16 + n16;

  for (int n = 0; n < NN; n++) {
    int t0 = n * CC;

    // ---- loads (all compile-time indexed; scheduler hoists into the chunk)
    bf8 kf[4][4], qf[4][4];
#pragma unroll
    for (int rt = 0; rt < 4; rt++) {
      size_t roff = (size_t)(t0 + rt * 16) * (HH * DKk);
#pragma unroll
      for (int s = 0; s < 4; s++) {
        kf[rt][s] = *(const bf8*)(knb + roff + s * 32);
        qf[rt][s] = *(const bf8*)(qnb + roff + s * 32);
      }
    }
    bf8 af[4][2];
#pragma unroll
    for (int rt = 0; rt < 4; rt++)
#pragma unroll
      for (int s = 0; s < 2; s++)
        af[rt][s] = *(const bf8*)(atb + (size_t)n * (CC * CC) + rt * 16 * CC + s * 32);
    bf8 tf[8][2];
#pragma unroll
    for (int mt = 0; mt < 8; mt++)
#pragma unroll
      for (int s = 0; s < 2; s++)
        tf[mt][s] = *(const bf8*)(ktb + (size_t)n * (DKk * CC) + mt * 16 * CC + s * 32);
    float vv[4][4];
#pragma unroll
    for (int rt = 0; rt < 4; rt++)
#pragma unroll
      for (int r = 0; r < 4; r++)
        vv[rt][r] = vbase[(size_t)(t0 + rt * 16 + r) * (HH * DVv)];
    float4 bb[4];
#pragma unroll
    for (int rt = 0; rt < 4; rt++)
      bb[rt] = *(const float4*)(btb + t0 + rt * 16);

    // ---- x = k @ S_old  (C-layout), o_inter = q @ S_old
    f4 xa[4], oi[4];
#pragma unroll
    for (int rt = 0; rt < 4; rt++) {
      f4 x0 = {0.f, 0.f, 0.f, 0.f}, x1 = {0.f, 0.f, 0.f, 0.f};
      f4 o0 = {0.f, 0.f, 0.f, 0.f}, o1 = {0.f, 0.f, 0.f, 0.f};
      x0 = __builtin_amdgcn_mfma_f32_16x16x32_bf16(kf[rt][0], bS0, x0, 0, 0, 0);
      x0 = __builtin_amdgcn_mfma_f32_16x16x32_bf16(kf[rt][1], bS1, x0, 0, 0, 0);
      x1 = __builtin_amdgcn_mfma_f32_16x16x32_bf16(kf[rt][2], bS2, x1, 0, 0, 0);
      x1 = __builtin_amdgcn_mfma_f32_16x16x32_bf16(kf[rt][3], bS3, x1, 0, 0, 0);
      o0 = __builtin_amdgcn_mfma_f32_16x16x32_bf16(qf[rt][0], bS0, o0, 0, 0, 0);
      o0 = __builtin_amdgcn_mfma_f32_16x16x32_bf16(qf[rt][1], bS1, o0, 0, 0, 0);
      o1 = __builtin_amdgcn_mfma_f32_16x16x32_bf16(qf[rt][2], bS2, o1, 0, 0, 0);
      o1 = __builtin_amdgcn_mfma_f32_16x16x32_bf16(qf[rt][3], bS3, o1, 0, 0, 0);
      xa[rt] = x0 + x1;
      oi[rt] = o0 + o1;
    }

    // ---- x = beta * (v - x); pack pairs -> wave-private LDS (C -> B layout)
#pragma unroll
    for (int rt = 0; rt < 4; rt++) {
      float e0 = bb[rt].x * (vv[rt][0] - xa[rt][0]);
      float e1 = bb[rt].y * (vv[rt][1] - xa[rt][1]);
      float e2 = bb[rt].z * (vv[rt][2] - xa[rt][2]);
      float e3 = bb[rt].w * (vv[rt][3] - xa[rt][3]);
      *(unsigned*)&xb[n16 * SW + rt * 16 + qd * 4 + 0] = packbf(e0, e1);
      *(unsigned*)&xb[n16 * SW + rt * 16 + qd * 4 + 2] = packbf(e2, e3);
    }
    // read back B-frags (same wave, in-order DS pipe; compiler waits lgkm)
    bf8 bx0 = *(const bf8*)&xb[n16 * SW + 0 + qd * 8];
    bf8 bx1 = *(const bf8*)&xb[n16 * SW + 32 + qd * 8];

    // ---- o = o_inter + AT @ x -> global (C-layout scalar stores)
#pragma unroll
    for (int rt = 0; rt < 4; rt++) {
      f4 oo = oi[rt];
      oo = __builtin_amdgcn_mfma_f32_16x16x32_bf16(af[rt][0], bx0, oo, 0, 0, 0);
      oo = __builtin_amdgcn_mfma_f32_16x16x32_bf16(af[rt][1], bx1, oo, 0, 0, 0);
#pragma unroll
      for (int r = 0; r < 4; r++)
        ob[(size_t)(t0 + rt * 16 + r) * (HH * DVv)] = oo[r];
    }

    // ---- S += Kt @ x   (8 C-tiles over dk)
#pragma unroll
    for (int mt = 0; mt < 8; mt++) {
      S[mt] = __builtin_amdgcn_mfma_f32_16x16x32_bf16(tf[mt][0], bx0, S[mt], 0, 0, 0);
      S[mt] = __builtin_amdgcn_mfma_f32_16x16x32_bf16(tf[mt][1], bx1, S[mt], 0, 0, 0);
    }

    // ---- S C-layout -> B-frags via wave-private LDS (for next chunk)
#pragma unroll
    for (int mt = 0; mt < 8; mt++) {
      *(unsigned*)&Sb[n16 * 136 + mt * 16 + qd * 4 + 0] = packbf(S[mt][0], S[mt][1]);
      *(unsigned*)&Sb[n16 * 136 + mt * 16 + qd * 4 + 2] = packbf(S[mt][2], S[mt][3]);
    }
    bS0 = *(const bf8*)&Sb[n16 * 136 + 0 + qd * 8];
    bS1 = *(const bf8*)&Sb[n16 * 136 + 32 + qd * 8];
    bS2 = *(const bf8*)&Sb[n16 * 136 + 64 + qd * 8];
    bS3 = *(const bf8*)&Sb[n16 * 136 + 96 + qd * 8];
  }
}

// ---------------------------------------------------------------------------
// K5: in-place on d_out: RMSNorm(o)*o_norm_w * swish(g), then per-head
//     projection via MFMA with pre-transposed Ppt[h][d][v] bf16.
// ---------------------------------------------------------------------------
__global__ __launch_bounds__(256) void k5_out(
    const float* __restrict__ graw, const float* __restrict__ onw,
    const unsigned short* __restrict__ Ppt, float* __restrict__ out) {
  int bi = blockIdx.x;                  // B*(T/32)*H = 4096
  int h = bi & (HH - 1);
  int tt = (bi >> 4) & 127;
  int b = bi >> 11;
  int t0 = tt * 32;
  int tid = threadIdx.x;
  int w = tid >> 6;
  int lane = tid & 63;
  int n16 = lane & 15;
  int qd = lane >> 4;

  __shared__ __align__(16) float so[32 * 132];            // 16896 B
  __shared__ float smul[32];
  __shared__ float snw[DVv];

  for (int r = 0; r < 16; r++) {
    int idx = r * 256 + tid;
    int t = idx >> 7, d = idx & 127;
    so[t * 132 + d] = out[((size_t)((b * TT + t0 + t) * HH + h)) * DVv + d];
  }
  if (tid < DVv) snw[tid] = onw[tid];
  __syncthreads();

  {
    int t = tid >> 3, l8 = tid & 7;
    float ss = 0.f;
    for (int j = 0; j < 16; j++) { float x = so[t * 132 + l8 + (j << 3)]; ss += x * x; }
    ss += __shfl_down(ss, 4, 8);
    ss += __shfl_down(ss, 2, 8);
    ss += __shfl_down(ss, 1, 8);
    if (l8 == 0) {
      float rms = rsqrtf(ss * (1.f / 128.f) + 1e-5f);
      float gv = graw[(size_t)((b * TT + t0 + t) * HH + h)];
      float sig = 1.f / (1.f + expf(-gv));
      smul[t] = rms * gv * sig;
    }
  }
  __syncthreads();
  for (int r = 0; r < 16; r++) {
    int idx = r * 256 + tid;
    int t = idx >> 7, d = idx & 127;
    so[t * 132 + d] *= smul[t] * snw[d];
  }
  __syncthreads();

  // ---- projection: out[t][d] = sum_v o~[t][v] * P[v][d]  (MFMA)
  {
    const unsigned short* Pb = Ppt + (size_t)h * (DVv * DKk);
    int dt0 = w * 2;                    // wave's two 16-col d-tiles
#pragma unroll
    for (int m = 0; m < 2; m++) {
      bf8 A[4];
#pragma unroll
      for (int ks = 0; ks < 4; ks++) {
        const float* sp = &so[(m * 16 + n16) * 132 + ks * 32 + qd * 8];
        float4 f0 = *(const float4*)sp;
        float4 f1 = *(const float4*)(sp + 4);
        A[ks][0] = (short)f2bf(f0.x); A[ks][1] = (short)f2bf(f0.y);
        A[ks][2] = (short)f2bf(f0.z); A[ks][3] = (short)f2bf(f0.w);
        A[ks][4] = (short)f2bf(f1.x); A[ks][5] = (short)f2bf(f1.y);
        A[ks][6] = (short)f2bf(f1.z); A[ks][7] = (short)f2bf(f1.w);
      }
#pragma unroll
      for (int dti = 0; dti < 2; dti++) {
        int dt = dt0 + dti;
        f4 acc = {0.f, 0.f, 0.f, 0.f};
#pragma unroll
        for (int ks = 0; ks < 4; ks++) {
          bf8 Bf = *(const bf8*)(Pb + (dt * 16 + n16) * 128 + ks * 32 + qd * 8);
          acc = __builtin_amdgcn_mfma_f32_16x16x32_bf16(A[ks], Bf, acc, 0, 0, 0);
        }
#pragma unroll
        for (int r = 0; r < 4; r++) {
          size_t go = ((size_t)(b * TT + t0 + m * 16 + qd * 4 + r)) * (HH * DKk)
                      + h * DKk + dt * 16 + n16;
          out[go] = acc[r];
        }
      }
    }
  }
}

// ---------------------------------------------------------------------------
extern "C" void kernel_launch(void* const* d_in, const int* in_sizes, int n_in,
                              void* d_out, int out_size, void* d_ws, size_t ws_size,
                              hipStream_t stream) {
  (void)in_sizes; (void)n_in; (void)out_size; (void)ws_size;
  const float* hab = (const float*)d_in[0];
  const float* hg  = (const float*)d_in[1];
  const float* q   = (const float*)d_in[2];
  const float* k   = (const float*)d_in[3];
  const float* v   = (const float*)d_in[4];
  const float* Wb  = (const float*)d_in[5];
  const float* Wg  = (const float*)d_in[6];
  const float* onw = (const float*)d_in[7];
  const float* opw = (const float*)d_in[8];
  float* out = (float*)d_out;

  // ws layout (bytes): beta 512K | graw 512K | qn 32M | kn 32M | ATg 16M
  //                    | Ktg 32M | Wtb 64K | Wtg 64K | Ppt 512K | bt 512K
  char* ws = (char*)d_ws;
  float* beta          = (float*)(ws);
  float* graw          = (float*)(ws + 524288);
  unsigned short* qn   = (unsigned short*)(ws + 1048576);
  unsigned short* kn   = (unsigned short*)(ws + 34603008);
  unsigned short* ATg  = (unsigned short*)(ws + 68157440);
  unsigned short* Ktg  = (unsigned short*)(ws + 84934656);
  unsigned short* Wtb  = (unsigned short*)(ws + 118489088);
  unsigned short* Wtg  = (unsigned short*)(ws + 118554624);
  unsigned short* Ppt  = (unsigned short*)(ws + 118620160);
  float* bt            = (float*)(ws + 119144448);

  hipLaunchKernelGGL(k0_wt, dim3(16), dim3(256), 0, stream,
                     Wb, Wg, Wtb, Wtg);
  hipLaunchKernelGGL(k0p_pt, dim3(HH), dim3(256), 0, stream,
                     opw, Ppt);
  hipLaunchKernelGGL(k1_beta_g, dim3(TT * BB / 16), dim3(256), 0, stream,
                     hab, hg, Wtb, Wtg, beta, graw, bt);
  hipLaunchKernelGGL(k2_l2norm, dim3(BB * TT * HH / 8), dim3(256), 0, stream,
                     q, k, qn, kn);
  hipLaunchKernelGGL(k3_chunk, dim3(BB * HH * NN), dim3(256), 0, stream,
                     qn, kn, beta, ATg, Ktg);
  hipLaunchKernelGGL(k4_scan, dim3(BB * HH * GG), dim3(64), 0, stream,
                     qn, kn, v, bt, ATg, Ktg, out);
  hipLaunchKernelGGL(k5_out, dim3(BB * (TT / 32) * HH), dim3(256), 0, stream,
                     graw, onw, Ppt, out);
}

// Round 6
// 523.677 us; speedup vs baseline: 1.6582x; 1.6582x over previous
//
#include <hip/hip_runtime.h>
#include <hip/hip_bf16.h>

// Problem constants (DeltaNet_6614249636545)
#define BB 2
#define TT 4096
#define HH 16
#define DKk 128
#define DVv 128
#define HIDD 2048
#define CC 64
#define NN 64          // TT / CC
#define GG 8           // dv 16-col windows in scan kernel
#define QSCALE 0.08838834764831845f  // 128^-0.5

static __device__ __forceinline__ unsigned short f2bf(float f) {
  unsigned u = __float_as_uint(f);
  u += 0x7fffu + ((u >> 16) & 1u);   // round-to-nearest-even
  return (unsigned short)(u >> 16);
}
static __device__ __forceinline__ float bf2f(unsigned short s) {
  return __uint_as_float(((unsigned)s) << 16);
}

// Barrier that drains ONLY LDS (lgkmcnt), leaving global loads in flight.
static __device__ __forceinline__ void barrier_lds_only() {
  asm volatile("s_waitcnt lgkmcnt(0)\n\ts_barrier" ::: "memory");
}

typedef short bf8 __attribute__((ext_vector_type(8)));
typedef short bf4 __attribute__((ext_vector_type(4)));
typedef float f4 __attribute__((ext_vector_type(4)));

static __device__ __forceinline__ bf4 pack_bf4(float a, float b, float c, float d) {
  bf4 r;
  r[0] = (short)f2bf(a); r[1] = (short)f2bf(b);
  r[2] = (short)f2bf(c); r[3] = (short)f2bf(d);
  return r;
}

// ---------------------------------------------------------------------------
// K0: transpose + bf16-cast projection weights: W[k][h] fp32 -> Wt[h][k] bf16
// ---------------------------------------------------------------------------
__global__ __launch_bounds__(256) void k0_wt(
    const float* __restrict__ Wb, const float* __restrict__ Wg,
    unsigned short* __restrict__ Wtb, unsigned short* __restrict__ Wtg) {
  int blk = blockIdx.x;
  const float* W = (blk < 8) ? Wb : Wg;
  unsigned short* Wt = (blk < 8) ? Wtb : Wtg;
  int k0 = (blk & 7) * 256;
  int tid = threadIdx.x;
  __shared__ unsigned short st[16][272];
  const float* p = W + (size_t)(k0 + tid) * HH;
#pragma unroll
  for (int h4 = 0; h4 < 4; h4++) {
    float4 x = *(const float4*)(p + h4 * 4);
    st[h4 * 4 + 0][tid] = f2bf(x.x);
    st[h4 * 4 + 1][tid] = f2bf(x.y);
    st[h4 * 4 + 2][tid] = f2bf(x.z);
    st[h4 * 4 + 3][tid] = f2bf(x.w);
  }
  __syncthreads();
  int h = tid >> 4, c = (tid & 15) << 4;
#pragma unroll
  for (int j = 0; j < 16; j++)
    Wt[(size_t)h * HIDD + k0 + c + j] = st[h][c + j];
}

// ---------------------------------------------------------------------------
// K0p: per-head transpose of o_proj_w: P[h][v][d] fp32 -> Ppt[h][d][v] bf16.
// ---------------------------------------------------------------------------
__global__ __launch_bounds__(256) void k0p_pt(
    const float* __restrict__ opw, unsigned short* __restrict__ Ppt) {
  int h = blockIdx.x;
  int tid = threadIdx.x;
  __shared__ unsigned short sp[128 * 132];
  const float* P = opw + (size_t)h * (DVv * DKk);
  for (int it = 0; it < 16; it++) {
    int idx = it * 256 + tid;            // 4096 float4 quads
    int vv = idx >> 5, d4 = (idx & 31) << 2;
    float4 x = *(const float4*)(P + vv * 128 + d4);
    sp[vv * 132 + d4 + 0] = f2bf(x.x);
    sp[vv * 132 + d4 + 1] = f2bf(x.y);
    sp[vv * 132 + d4 + 2] = f2bf(x.z);
    sp[vv * 132 + d4 + 3] = f2bf(x.w);
  }
  __syncthreads();
  unsigned short* dst = Ppt + (size_t)h * (DVv * DKk);
  for (int it = 0; it < 8; it++) {
    int idx = it * 256 + tid;            // 2048 groups of 8
    int d = idx >> 4, v8 = (idx & 15) << 3;
    unsigned short tmp[8];
#pragma unroll
    for (int j = 0; j < 8; j++) tmp[j] = sp[(v8 + j) * 132 + d];
    *(uint4*)&dst[d * 128 + v8] = *(uint4*)tmp;
  }
}

// ---------------------------------------------------------------------------
// K1 (MFMA): beta = sigmoid(hab @ Wb), graw = hg @ Wg as skinny GEMM.
// Also writes bt[b][h][T] (beta contiguous in t) for k4's float4 loads.
// ---------------------------------------------------------------------------
__global__ __launch_bounds__(256) void k1_beta_g(
    const float* __restrict__ hab, const float* __restrict__ hg,
    const unsigned short* __restrict__ Wtb, const unsigned short* __restrict__ Wtg,
    float* __restrict__ beta, float* __restrict__ graw,
    float* __restrict__ bt) {
  int tile = blockIdx.x;               // 512 tiles of 16 tokens
  int tid = threadIdx.x;
  int w = tid >> 6, lane = tid & 63;
  int proj = w >> 1, ks = w & 1;
  int n16 = lane & 15, qd = lane >> 4;
  const float* hid = proj ? hg : hab;
  const unsigned short* Wt = proj ? Wtg : Wtb;
  size_t rowbase = (size_t)(tile * 16 + n16) * HIDD;
  int k0 = ks * 1024;

  f4 acc = {0.f, 0.f, 0.f, 0.f};
  for (int s = 0; s < 32; s++) {
    int kk = k0 + s * 32 + qd * 8;
    const float* hp = hid + rowbase + kk;
    float4 h0 = *(const float4*)hp;
    float4 h1 = *(const float4*)(hp + 4);
    bf8 a;
    a[0] = (short)f2bf(h0.x); a[1] = (short)f2bf(h0.y);
    a[2] = (short)f2bf(h0.z); a[3] = (short)f2bf(h0.w);
    a[4] = (short)f2bf(h1.x); a[5] = (short)f2bf(h1.y);
    a[6] = (short)f2bf(h1.z); a[7] = (short)f2bf(h1.w);
    bf8 b = *(const bf8*)&Wt[(size_t)n16 * HIDD + kk];
    acc = __builtin_amdgcn_mfma_f32_16x16x32_bf16(a, b, acc, 0, 0, 0);
  }

  __shared__ float red[2][16][17];
  if (ks == 1) {
#pragma unroll
    for (int r = 0; r < 4; r++) red[proj][qd * 4 + r][n16] = acc[r];
  }
  __syncthreads();
  if (ks == 0) {
#pragma unroll
    for (int r = 0; r < 4; r++) {
      float s = acc[r] + red[proj][qd * 4 + r][n16];
      int tg = tile * 16 + qd * 4 + r;        // global token index in [0, B*T)
      size_t t = (size_t)tg * HH + n16;
      if (proj == 0) {
        float bv = 1.f / (1.f + expf(-s));
        beta[t] = bv;
        int bb = tg >> 12;                    // / TT
        int ti = tg & (TT - 1);
        bt[((size_t)(bb * HH + n16)) * TT + ti] = bv;
      } else {
        graw[t] = s;
      }
    }
  }
}

// ---------------------------------------------------------------------------
// K2: l2norm(q)*scale -> qn (bf16), l2norm(k) -> kn (bf16)
// ---------------------------------------------------------------------------
__global__ __launch_bounds__(256) void k2_l2norm(
    const float* __restrict__ q, const float* __restrict__ k,
    unsigned short* __restrict__ qn, unsigned short* __restrict__ kn) {
  int lane = threadIdx.x & 63, wave = threadIdx.x >> 6;
  for (int u = 0; u < 2; u++) {
    int vec = blockIdx.x * 8 + wave * 2 + u;
    size_t off = (size_t)vec * 64 + lane;
    float2 q2 = ((const float2*)q)[off];
    float2 k2 = ((const float2*)k)[off];
    float sq = q2.x * q2.x + q2.y * q2.y;
    float sk = k2.x * k2.x + k2.y * k2.y;
#pragma unroll
    for (int m = 32; m; m >>= 1) { sq += __shfl_xor(sq, m); sk += __shfl_xor(sk, m); }
    float rq = rsqrtf(sq + 1e-6f) * QSCALE;
    float rk = rsqrtf(sk + 1e-6f);
    unsigned pq = (unsigned)f2bf(q2.x * rq) | ((unsigned)f2bf(q2.y * rq) << 16);
    unsigned pk = (unsigned)f2bf(k2.x * rk) | ((unsigned)f2bf(k2.y * rk) << 16);
    ((unsigned*)qn)[off] = pq;
    ((unsigned*)kn)[off] = pk;
  }
}

// ---------------------------------------------------------------------------
// K3 (MFMA): per chunk: attn = tril(q k^T), A = tril(k_beta k^T,-1),
//   T = (I+A)^{-1} via nilpotent doubling, then:
//     ATg = attn @ T   [64 x 64]
//     Ktg = k^T @ T    [128 x 64] (row-major in dk)
// ---------------------------------------------------------------------------
#define SW 72          // stride (shorts) of 64x64 bf16 mats
#define K3_M0R 8704
#define K3_M0T 13312
#define K3_M1R 17920
#define K3_M1T 22528
#define K3_TB  27136   // T^T (col-major shadow of T), bf16
#define K3_ARENA 31744 // 63488 B

__global__ __launch_bounds__(256) void k3_chunk(
    const unsigned short* __restrict__ qn, const unsigned short* __restrict__ kn,
    const float* __restrict__ beta,
    unsigned short* __restrict__ ATg, unsigned short* __restrict__ Ktg) {
  int cid = blockIdx.x;
  int n = cid & (NN - 1);
  int bh = cid / NN;
  int h = bh & (HH - 1);
  int b = bh / HH;
  int tid = threadIdx.x;
  int w = tid >> 6;
  int lane = tid & 63;
  int n16 = lane & 15;
  int qd = lane >> 4;
  int r0 = w * 16;

  __shared__ __align__(16) unsigned short arena[K3_ARENA];
  __shared__ float sb[CC];
  unsigned short* sk = arena;           // [c][dk] stride 136, LIVE throughout
  unsigned short* sq = arena + 8704;    // aliased by M buffers after attn

  int t0 = n * CC;
#pragma unroll
  for (int p = 0; p < 4; p++) {
    int id = p * 256 + tid, row = id >> 4, c8 = (id & 15) << 3;
    size_t g = ((size_t)((b * TT + t0 + row) * HH + h)) * DKk + c8;
    *(uint4*)&sk[row * 136 + c8] = *(const uint4*)(kn + g);
    *(uint4*)&sq[row * 136 + c8] = *(const uint4*)(qn + g);
  }
  if (tid < CC) sb[tid] = beta[(size_t)((b * TT + t0 + tid) * HH + h)];
  __syncthreads();

  // ---- attn = q k^T and raw kk = k k^T   (MFMA, K=128)
  f4 at[4], mk[4];
#pragma unroll
  for (int ct = 0; ct < 4; ct++) { at[ct] = (f4){0,0,0,0}; mk[ct] = (f4){0,0,0,0}; }
#pragma unroll
  for (int s = 0; s < 4; s++) {
    bf8 aq = *(const bf8*)&sq[(r0 + n16) * 136 + s * 32 + qd * 8];
    bf8 ak = *(const bf8*)&sk[(r0 + n16) * 136 + s * 32 + qd * 8];
#pragma unroll
    for (int ct = 0; ct < 4; ct++) {
      bf8 bk = *(const bf8*)&sk[(ct * 16 + n16) * 136 + s * 32 + qd * 8];
      at[ct] = __builtin_amdgcn_mfma_f32_16x16x32_bf16(aq, bk, at[ct], 0, 0, 0);
      mk[ct] = __builtin_amdgcn_mfma_f32_16x16x32_bf16(ak, bk, mk[ct], 0, 0, 0);
    }
  }

  f4 tf[4];
  float mpv[4][4];
#pragma unroll
  for (int ct = 0; ct < 4; ct++) {
#pragma unroll
    for (int r = 0; r < 4; r++) {
      int i = r0 + qd * 4 + r, j = ct * 16 + n16;
      at[ct][r] = (j <= i) ? at[ct][r] : 0.f;      // masked attn kept in regs
      float mp = (j < i) ? -sb[i] * mk[ct][r] : 0.f;
      mpv[ct][r] = mp;
      tf[ct][r] = (i == j) ? 1.f : mp;
    }
  }
  __syncthreads();   // reads of sq done; M region usable

#pragma unroll
  for (int ct = 0; ct < 4; ct++) {
#pragma unroll
    for (int r = 0; r < 4; r++) {
      int i = r0 + qd * 4 + r, j = ct * 16 + n16;
      unsigned short hm = f2bf(mpv[ct][r]);
      arena[K3_M0R + i * SW + j] = hm;
      arena[K3_M0T + j * SW + i] = hm;
      arena[K3_TB + j * SW + i] = f2bf(tf[ct][r]);
    }
  }
  __syncthreads();

  int p = 0;
  for (int it = 1; it <= 5; it++) {
    int mrp = p ? K3_M1R : K3_M0R, mtp = p ? K3_M1T : K3_M0T;
    int mrn = p ? K3_M0R : K3_M1R, mtn = p ? K3_M0T : K3_M1T;
    f4 nr[4];
#pragma unroll
    for (int ct = 0; ct < 4; ct++) nr[ct] = (f4){0,0,0,0};
#pragma unroll
    for (int s = 0; s < 2; s++) {
      bf8 a = *(const bf8*)&arena[mrp + (r0 + n16) * SW + s * 32 + qd * 8];
#pragma unroll
      for (int ct = 0; ct < 4; ct++) {
        bf8 bb = *(const bf8*)&arena[mtp + (ct * 16 + n16) * SW + s * 32 + qd * 8];
        nr[ct] = __builtin_amdgcn_mfma_f32_16x16x32_bf16(a, bb, nr[ct], 0, 0, 0);
      }
    }
#pragma unroll
    for (int ct = 0; ct < 4; ct++) {
#pragma unroll
      for (int r = 0; r < 4; r++) {
        int i = r0 + qd * 4 + r, j = ct * 16 + n16;
        unsigned short hm = f2bf(nr[ct][r]);
        arena[mrn + i * SW + j] = hm;
        arena[mtn + j * SW + i] = hm;
      }
    }
    __syncthreads();  // B1

    // phase B: Tf += N · T
#pragma unroll
    for (int s = 0; s < 2; s++) {
      bf8 a = *(const bf8*)&arena[mrn + (r0 + n16) * SW + s * 32 + qd * 8];
#pragma unroll
      for (int ct = 0; ct < 4; ct++) {
        bf8 bb = *(const bf8*)&arena[K3_TB + (ct * 16 + n16) * SW + s * 32 + qd * 8];
        tf[ct] = __builtin_amdgcn_mfma_f32_16x16x32_bf16(a, bb, tf[ct], 0, 0, 0);
      }
    }
    __syncthreads();  // B2

    if (it < 5) {
#pragma unroll
      for (int ct = 0; ct < 4; ct++) {
#pragma unroll
        for (int r = 0; r < 4; r++) {
          int i = r0 + qd * 4 + r, j = ct * 16 + n16;
          arena[K3_TB + j * SW + i] = f2bf(tf[ct][r]);
        }
      }
    }
    p = 1 - p;
  }

  // ---- post-loop: attn -> M0R (dead), FINAL T^T -> TB
#pragma unroll
  for (int ct = 0; ct < 4; ct++) {
#pragma unroll
    for (int r = 0; r < 4; r++) {
      int i = r0 + qd * 4 + r, j = ct * 16 + n16;
      arena[K3_M0R + i * SW + j] = f2bf(at[ct][r]);
      arena[K3_TB + j * SW + i] = f2bf(tf[ct][r]);
    }
  }
  __syncthreads();

  // ---- ATg = attn @ T
  {
    f4 ac[4];
#pragma unroll
    for (int ct = 0; ct < 4; ct++) ac[ct] = (f4){0,0,0,0};
#pragma unroll
    for (int s = 0; s < 2; s++) {
      bf8 a = *(const bf8*)&arena[K3_M0R + (r0 + n16) * SW + s * 32 + qd * 8];
#pragma unroll
      for (int ct = 0; ct < 4; ct++) {
        bf8 bb = *(const bf8*)&arena[K3_TB + (ct * 16 + n16) * SW + s * 32 + qd * 8];
        ac[ct] = __builtin_amdgcn_mfma_f32_16x16x32_bf16(a, bb, ac[ct], 0, 0, 0);
      }
    }
    size_t abase = (size_t)cid * (CC * CC);
#pragma unroll
    for (int ct = 0; ct < 4; ct++)
#pragma unroll
      for (int r = 0; r < 4; r++)
        ATg[abase + (r0 + qd * 4 + r) * CC + ct * 16 + n16] = f2bf(ac[ct][r]);
  }

  // ---- Ktg = k^T @ T   (wave w owns dk rows w*32..w*32+31)
  {
    size_t kbase = (size_t)cid * (DKk * CC);
#pragma unroll
    for (int t = 0; t < 2; t++) {
      int dkt = w * 32 + t * 16;
      f4 ac[4];
#pragma unroll
      for (int ct = 0; ct < 4; ct++) ac[ct] = (f4){0,0,0,0};
#pragma unroll
      for (int s = 0; s < 2; s++) {
        bf8 a;
#pragma unroll
        for (int jj = 0; jj < 8; jj++)
          a[jj] = (short)sk[(s * 32 + qd * 8 + jj) * 136 + dkt + n16];
#pragma unroll
        for (int ct = 0; ct < 4; ct++) {
          bf8 bb = *(const bf8*)&arena[K3_TB + (ct * 16 + n16) * SW + s * 32 + qd * 8];
          ac[ct] = __builtin_amdgcn_mfma_f32_16x16x32_bf16(a, bb, ac[ct], 0, 0, 0);
        }
      }
#pragma unroll
      for (int ct = 0; ct < 4; ct++)
#pragma unroll
        for (int r = 0; r < 4; r++)
          Ktg[kbase + (dkt + qd * 4 + r) * CC + ct * 16 + n16] = f2bf(ac[ct][r]);
    }
  }
}

// ---------------------------------------------------------------------------
// K4 (MFMA): R10 producer/consumer wave split. 512-thread blocks, grid 256.
// Waves 0-3 (chain): x(n) = beta*(v - k@S(n-1)); S(n) += Kt@x(n). The ONLY
// work on the serial S-recurrence. Waves 4-7 (o-group): one chunk behind,
// o(n-1) = q(n-1)@S(n-2) + AT@x(n-1) + global stores -- fills the chain's
// stall cycles on the same SIMDs. S^T and x^T double-buffered in LDS;
// o-group reads land in the first barrier interval, chain writes in the
// second -> race-free by parity. Chain waves run at s_setprio(1).
// ---------------------------------------------------------------------------
struct K4F {
  bf8 k0, k1, k2, k3;      // chain: kn rows r0+n16, 4 K-slices
  bf8 t0, t1, t2, t3;      // chain: Ktg rows dkbase+n16 / dkbase+16+n16
  float4 vv;               // chain: v[t0+r0+n16][j0+qd*4..+4]
  float4 bb;               // chain: bt rows r0+qd*4..+3 (contiguous)
  bf8 q0, q1, q2, q3;      // o: qn rows r0+n16
  bf8 a0, a1;              // o: ATg rows r0+n16
};

static __device__ __forceinline__ void k4_pref_chain(
    K4F& F, int n, const unsigned short* knb, const unsigned short* ktb,
    const float* vb, const float* btb) {
  const unsigned short* kp = knb + (size_t)n * (CC * HH * DKk);
  F.k0 = *(const bf8*)(kp);
  F.k1 = *(const bf8*)(kp + 32);
  F.k2 = *(const bf8*)(kp + 64);
  F.k3 = *(const bf8*)(kp + 96);
  const unsigned short* tp = ktb + (size_t)n * (DKk * CC);
  F.t0 = *(const bf8*)(tp);
  F.t1 = *(const bf8*)(tp + 32);
  F.t2 = *(const bf8*)(tp + 1024);
  F.t3 = *(const bf8*)(tp + 1056);
  F.vv = *(const float4*)(vb + (size_t)n * (CC * HH * DVv));
  F.bb = *(const float4*)(btb + n * CC);
}

static __device__ __forceinline__ void k4_pref_o(
    K4F& F, int n, const unsigned short* qnb, const unsigned short* atb) {
  const unsigned short* qp = qnb + (size_t)n * (CC * HH * DKk);
  F.q0 = *(const bf8*)(qp);
  F.q1 = *(const bf8*)(qp + 32);
  F.q2 = *(const bf8*)(qp + 64);
  F.q3 = *(const bf8*)(qp + 96);
  const unsigned short* ap = atb + (size_t)n * (CC * CC);
  F.a0 = *(const bf8*)(ap);
  F.a1 = *(const bf8*)(ap + 32);
}

static __device__ __forceinline__ void k4_body(
    const K4F& Fc, K4F& Fn, int i, int grp, bool pfc, bool pfo, bool odo,
    f4& S0, f4& S1,
    unsigned short* xTc, const unsigned short* xTo,
    const unsigned short* sSrd_c, unsigned short* sSwr_c,
    const unsigned short* sSrd_o,
    float* opb,
    int n16, int qd, int r0, int dkbase,
    const unsigned short* knb, const unsigned short* ktb,
    const float* vb, const float* btb,
    const unsigned short* qnb, const unsigned short* atb) {
  if (grp == 0) {
    // stage v(i) into xT[i&1] (this wave's 16 columns; fenced by B2 of i-1)
    int col = r0 + n16;
    xTc[(qd * 4 + 0) * SW + col] = f2bf(Fc.vv.x);
    xTc[(qd * 4 + 1) * SW + col] = f2bf(Fc.vv.y);
    xTc[(qd * 4 + 2) * SW + col] = f2bf(Fc.vv.z);
    xTc[(qd * 4 + 3) * SW + col] = f2bf(Fc.vv.w);
  }
  barrier_lds_only();   // B1: S^T(i-1) + v staging visible

  if (grp == 0) {
    if (pfc) k4_pref_chain(Fn, i + 1, knb, ktb, vb, btb);
    // ---- chain phase1: x = beta*(v - k@S(i-1)), wave-local RMW of xTc
    bf8 bS0 = *(const bf8*)&sSrd_c[n16 * 136 + 0  + qd * 8];
    bf8 bS1 = *(const bf8*)&sSrd_c[n16 * 136 + 32 + qd * 8];
    bf8 bS2 = *(const bf8*)&sSrd_c[n16 * 136 + 64 + qd * 8];
    bf8 bS3 = *(const bf8*)&sSrd_c[n16 * 136 + 96 + qd * 8];
    f4 xa = {0.f, 0.f, 0.f, 0.f}, xc = {0.f, 0.f, 0.f, 0.f};
    xa = __builtin_amdgcn_mfma_f32_16x16x32_bf16(Fc.k0, bS0, xa, 0, 0, 0);
    xa = __builtin_amdgcn_mfma_f32_16x16x32_bf16(Fc.k1, bS1, xa, 0, 0, 0);
    xc = __builtin_amdgcn_mfma_f32_16x16x32_bf16(Fc.k2, bS2, xc, 0, 0, 0);
    xc = __builtin_amdgcn_mfma_f32_16x16x32_bf16(Fc.k3, bS3, xc, 0, 0, 0);
    bf4 vv4 = *(const bf4*)&xTc[n16 * SW + r0 + qd * 4];
    float xr[4];
    xr[0] = Fc.bb.x * (bf2f((unsigned short)vv4[0]) - (xa[0] + xc[0]));
    xr[1] = Fc.bb.y * (bf2f((unsigned short)vv4[1]) - (xa[1] + xc[1]));
    xr[2] = Fc.bb.z * (bf2f((unsigned short)vv4[2]) - (xa[2] + xc[2]));
    xr[3] = Fc.bb.w * (bf2f((unsigned short)vv4[3]) - (xa[3] + xc[3]));
    *(bf4*)&xTc[n16 * SW + r0 + qd * 4] = pack_bf4(xr[0], xr[1], xr[2], xr[3]);
  } else {
    if (pfo) k4_pref_o(Fn, i, qnb, atb);
    if (odo) {
      // ---- o-group: o(i-1) = q(i-1)@S(i-2) + AT(i-1)@x(i-1); store.
      // All LDS reads complete before B2 (sSrd_o is chain's write target).
      bf8 oS0 = *(const bf8*)&sSrd_o[n16 * 136 + 0  + qd * 8];
      bf8 oS1 = *(const bf8*)&sSrd_o[n16 * 136 + 32 + qd * 8];
      bf8 oS2 = *(const bf8*)&sSrd_o[n16 * 136 + 64 + qd * 8];
      bf8 oS3 = *(const bf8*)&sSrd_o[n16 * 136 + 96 + qd * 8];
      bf8 bx0 = *(const bf8*)&xTo[n16 * SW + 0  + qd * 8];
      bf8 bx1 = *(const bf8*)&xTo[n16 * SW + 32 + qd * 8];
      f4 oa = {0.f, 0.f, 0.f, 0.f}, ob = {0.f, 0.f, 0.f, 0.f};
      oa = __builtin_amdgcn_mfma_f32_16x16x32_bf16(Fc.q0, oS0, oa, 0, 0, 0);
      oa = __builtin_amdgcn_mfma_f32_16x16x32_bf16(Fc.q1, oS1, oa, 0, 0, 0);
      ob = __builtin_amdgcn_mfma_f32_16x16x32_bf16(Fc.q2, oS2, ob, 0, 0, 0);
      ob = __builtin_amdgcn_mfma_f32_16x16x32_bf16(Fc.q3, oS3, ob, 0, 0, 0);
      f4 oo = oa + ob;
      oo = __builtin_amdgcn_mfma_f32_16x16x32_bf16(Fc.a0, bx0, oo, 0, 0, 0);
      oo = __builtin_amdgcn_mfma_f32_16x16x32_bf16(Fc.a1, bx1, oo, 0, 0, 0);
      float* opn = opb + (size_t)(i - 1) * (CC * HH * DVv);
#pragma unroll
      for (int r = 0; r < 4; r++) opn[r * (HH * DVv)] = oo[r];
    }
  }
  barrier_lds_only();   // B2: x(i) visible; o-group's S(i-2) reads done

  if (grp == 0) {
    // ---- chain phase2: S(i) = S(i-1) + Kt@x(i); publish S^T(i)
    bf8 bx0 = *(const bf8*)&xTc[n16 * SW + 0  + qd * 8];
    bf8 bx1 = *(const bf8*)&xTc[n16 * SW + 32 + qd * 8];
    S0 = __builtin_amdgcn_mfma_f32_16x16x32_bf16(Fc.t0, bx0, S0, 0, 0, 0);
    S0 = __builtin_amdgcn_mfma_f32_16x16x32_bf16(Fc.t1, bx1, S0, 0, 0, 0);
    S1 = __builtin_amdgcn_mfma_f32_16x16x32_bf16(Fc.t2, bx0, S1, 0, 0, 0);
    S1 = __builtin_amdgcn_mfma_f32_16x16x32_bf16(Fc.t3, bx1, S1, 0, 0, 0);
    *(bf4*)&sSwr_c[n16 * 136 + dkbase + qd * 4] =
        pack_bf4(S0[0], S0[1], S0[2], S0[3]);
    *(bf4*)&sSwr_c[n16 * 136 + dkbase + 16 + qd * 4] =
        pack_bf4(S1[0], S1[1], S1[2], S1[3]);
  }
}

__global__ __launch_bounds__(512, 1) void k4_scan(
    const unsigned short* __restrict__ qn, const unsigned short* __restrict__ kn,
    const float* __restrict__ v, const float* __restrict__ bt,
    const unsigned short* __restrict__ ATg, const unsigned short* __restrict__ Ktg,
    float* __restrict__ o) {
  int bi = blockIdx.x;                 // jg*32 + bh (same-bh blocks adjacent)
  int jg = bi >> 5;
  int bh = bi & 31;
  int h = bh & (HH - 1);
  int b = bh >> 4;
  int tid = threadIdx.x;
  int j0 = jg * 16;
  int w = tid >> 6;
  int grp = w >> 2;                    // 0 = chain, 1 = o-group
  int wl = w & 3;
  int lane = tid & 63;
  int n16 = lane & 15;
  int qd = lane >> 4;
  int r0 = wl * 16;                    // row tile of this wave (both groups)
  int dkbase = wl * 32;                // chain: S dk-rows owned

  __shared__ __align__(16) unsigned short sSb[2][16 * 136];  // S^T dbuf
  __shared__ __align__(16) unsigned short sxT[2][16 * SW];   // x^T dbuf

  f4 S0 = {0.f, 0.f, 0.f, 0.f}, S1 = {0.f, 0.f, 0.f, 0.f};
  for (int i2 = tid; i2 < 2 * 16 * 136; i2 += 512) ((unsigned short*)sSb)[i2] = 0;

  size_t bhN = (size_t)(b * HH + h) * NN;
  const unsigned short* knb =
      kn + ((size_t)((b * TT + r0 + n16) * HH + h)) * DKk + qd * 8;
  const unsigned short* qnb =
      qn + ((size_t)((b * TT + r0 + n16) * HH + h)) * DKk + qd * 8;
  const unsigned short* atb = ATg + bhN * (CC * CC) + (r0 + n16) * 64 + qd * 8;
  const unsigned short* ktb = Ktg + bhN * (DKk * CC) + (dkbase + n16) * 64 + qd * 8;
  const float* vb =
      v + ((size_t)((b * TT + r0 + n16) * HH + h)) * DVv + j0 + qd * 4;
  const float* btb = bt + (size_t)(b * HH + h) * TT + r0 + qd * 4;
  float* opb =
      o + ((size_t)((b * TT + r0 + qd * 4) * HH + h)) * DVv + j0 + n16;

  K4F FA, FB;
  if (grp == 0) {
    k4_pref_chain(FA, 0, knb, ktb, vb, btb);
    __builtin_amdgcn_s_setprio(1);     // chain waves = critical path
  }

  for (int i = 0; i < NN; i += 2) {
    k4_body(FA, FB, i, grp, i + 1 < NN, true, i > 0, S0, S1,
            sxT[0], sxT[1], sSb[1], sSb[0], sSb[0], opb,
            n16, qd, r0, dkbase, knb, ktb, vb, btb, qnb, atb);
    k4_body(FB, FA, i + 1, grp, i + 2 < NN, i + 1 < NN, true, S0, S1,
            sxT[1], sxT[0], sSb[0], sSb[1], sSb[1], opb,
            n16, qd, r0, dkbase, knb, ktb, vb, btb, qnb, atb);
  }
  // epilogue interval i = NN: o-group emits o(NN-1). x(NN-1) and S(NN-2)
  // already published and fenced by the loop's final barriers.
  if (grp == 1) {
    bf8 oS0 = *(const bf8*)&sSb[0][n16 * 136 + 0  + qd * 8];
    bf8 oS1 = *(const bf8*)&sSb[0][n16 * 136 + 32 + qd * 8];
    bf8 oS2 = *(const bf8*)&sSb[0][n16 * 136 + 64 + qd * 8];
    bf8 oS3 = *(const bf8*)&sSb[0][n16 * 136 + 96 + qd * 8];
    bf8 bx0 = *(const bf8*)&sxT[1][n16 * SW + 0  + qd * 8];
    bf8 bx1 = *(const bf8*)&sxT[1][n16 * SW + 32 + qd * 8];
    f4 oa = {0.f, 0.f, 0.f, 0.f}, ob = {0.f, 0.f, 0.f, 0.f};
    oa = __builtin_amdgcn_mfma_f32_16x16x32_bf16(FA.q0, oS0, oa, 0, 0, 0);
    oa = __builtin_amdgcn_mfma_f32_16x16x32_bf16(FA.q1, oS1, oa, 0, 0, 0);
    ob = __builtin_amdgcn_mfma_f32_16x16x32_bf16(FA.q2, oS2, ob, 0, 0, 0);
    ob = __builtin_amdgcn_mfma_f32_16x16x32_bf16(FA.q3, oS3, ob, 0, 0, 0);
    f4 oo = oa + ob;
    oo = __builtin_amdgcn_mfma_f32_16x16x32_bf16(FA.a0, bx0, oo, 0, 0, 0);
    oo = __builtin_amdgcn_mfma_f32_16x16x32_bf16(FA.a1, bx1, oo, 0, 0, 0);
    float* opn = opb + (size_t)(NN - 1) * (CC * HH * DVv);
#pragma unroll
    for (int r = 0; r < 4; r++) opn[r * (HH * DVv)] = oo[r];
  }
}

// ---------------------------------------------------------------------------
// K5: in-place on d_out: RMSNorm(o)*o_norm_w * swish(g), then per-head
//     projection via MFMA with pre-transposed Ppt[h][d][v] bf16.
// ---------------------------------------------------------------------------
__global__ __launch_bounds__(256) void k5_out(
    const float* __restrict__ graw, const float* __restrict__ onw,
    const unsigned short* __restrict__ Ppt, float* __restrict__ out) {
  int bi = blockIdx.x;                  // B*(T/32)*H = 4096
  int h = bi & (HH - 1);
  int tt = (bi >> 4) & 127;
  int b = bi >> 11;
  int t0 = tt * 32;
  int tid = threadIdx.x;
  int w = tid >> 6;
  int lane = tid & 63;
  int n16 = lane & 15;
  int qd = lane >> 4;

  __shared__ __align__(16) float so[32 * 132];            // 16896 B
  __shared__ float smul[32];
  __shared__ float snw[DVv];

  for (int r = 0; r < 16; r++) {
    int idx = r * 256 + tid;
    int t = idx >> 7, d = idx & 127;
    so[t * 132 + d] = out[((size_t)((b * TT + t0 + t) * HH + h)) * DVv + d];
  }
  if (tid < DVv) snw[tid] = onw[tid];
  __syncthreads();

  {
    int t = tid >> 3, l8 = tid & 7;
    float ss = 0.f;
    for (int j = 0; j < 16; j++) { float x = so[t * 132 + l8 + (j << 3)]; ss += x * x; }
    ss += __shfl_down(ss, 4, 8);
    ss += __shfl_down(ss, 2, 8);
    ss += __shfl_down(ss, 1, 8);
    if (l8 == 0) {
      float rms = rsqrtf(ss * (1.f / 128.f) + 1e-5f);
      float gv = graw[(size_t)((b * TT + t0 + t) * HH + h)];
      float sig = 1.f / (1.f + expf(-gv));
      smul[t] = rms * gv * sig;
    }
  }
  __syncthreads();
  for (int r = 0; r < 16; r++) {
    int idx = r * 256 + tid;
    int t = idx >> 7, d = idx & 127;
    so[t * 132 + d] *= smul[t] * snw[d];
  }
  __syncthreads();

  // ---- projection: out[t][d] = sum_v o~[t][v] * P[v][d]  (MFMA)
  {
    const unsigned short* Pb = Ppt + (size_t)h * (DVv * DKk);
    int dt0 = w * 2;                    // wave's two 16-col d-tiles
#pragma unroll
    for (int m = 0; m < 2; m++) {
      bf8 A[4];
#pragma unroll
      for (int ks = 0; ks < 4; ks++) {
        const float* sp = &so[(m * 16 + n16) * 132 + ks * 32 + qd * 8];
        float4 f0 = *(const float4*)sp;
        float4 f1 = *(const float4*)(sp + 4);
        A[ks][0] = (short)f2bf(f0.x); A[ks][1] = (short)f2bf(f0.y);
        A[ks][2] = (short)f2bf(f0.z); A[ks][3] = (short)f2bf(f0.w);
        A[ks][4] = (short)f2bf(f1.x); A[ks][5] = (short)f2bf(f1.y);
        A[ks][6] = (short)f2bf(f1.z); A[ks][7] = (short)f2bf(f1.w);
      }
#pragma unroll
      for (int dti = 0; dti < 2; dti++) {
        int dt = dt0 + dti;
        f4 acc = {0.f, 0.f, 0.f, 0.f};
#pragma unroll
        for (int ks = 0; ks < 4; ks++) {
          bf8 Bf = *(const bf8*)(Pb + (dt * 16 + n16) * 128 + ks * 32 + qd * 8);
          acc = __builtin_amdgcn_mfma_f32_16x16x32_bf16(A[ks], Bf, acc, 0, 0, 0);
        }
#pragma unroll
        for (int r = 0; r < 4; r++) {
          size_t go = ((size_t)(b * TT + t0 + m * 16 + qd * 4 + r)) * (HH * DKk)
                      + h * DKk + dt * 16 + n16;
          out[go] = acc[r];
        }
      }
    }
  }
}

// ---------------------------------------------------------------------------
extern "C" void kernel_launch(void* const* d_in, const int* in_sizes, int n_in,
                              void* d_out, int out_size, void* d_ws, size_t ws_size,
                              hipStream_t stream) {
  (void)in_sizes; (void)n_in; (void)out_size; (void)ws_size;
  const float* hab = (const float*)d_in[0];
  const float* hg  = (const float*)d_in[1];
  const float* q   = (const float*)d_in[2];
  const float* k   = (const float*)d_in[3];
  const float* v   = (const float*)d_in[4];
  const float* Wb  = (const float*)d_in[5];
  const float* Wg  = (const float*)d_in[6];
  const float* onw = (const float*)d_in[7];
  const float* opw = (const float*)d_in[8];
  float* out = (float*)d_out;

  // ws layout (bytes): beta 512K | graw 512K | qn 32M | kn 32M | ATg 16M
  //                    | Ktg 32M | Wtb 64K | Wtg 64K | Ppt 512K | bt 512K
  char* ws = (char*)d_ws;
  float* beta          = (float*)(ws);
  float* graw          = (float*)(ws + 524288);
  unsigned short* qn   = (unsigned short*)(ws + 1048576);
  unsigned short* kn   = (unsigned short*)(ws + 34603008);
  unsigned short* ATg  = (unsigned short*)(ws + 68157440);
  unsigned short* Ktg  = (unsigned short*)(ws + 84934656);
  unsigned short* Wtb  = (unsigned short*)(ws + 118489088);
  unsigned short* Wtg  = (unsigned short*)(ws + 118554624);
  unsigned short* Ppt  = (unsigned short*)(ws + 118620160);
  float* bt            = (float*)(ws + 119144448);

  hipLaunchKernelGGL(k0_wt, dim3(16), dim3(256), 0, stream,
                     Wb, Wg, Wtb, Wtg);
  hipLaunchKernelGGL(k0p_pt, dim3(HH), dim3(256), 0, stream,
                     opw, Ppt);
  hipLaunchKernelGGL(k1_beta_g, dim3(TT * BB / 16), dim3(256), 0, stream,
                     hab, hg, Wtb, Wtg, beta, graw, bt);
  hipLaunchKernelGGL(k2_l2norm, dim3(BB * TT * HH / 8), dim3(256), 0, stream,
                     q, k, qn, kn);
  hipLaunchKernelGGL(k3_chunk, dim3(BB * HH * NN), dim3(256), 0, stream,
                     qn, kn, beta, ATg, Ktg);
  hipLaunchKernelGGL(k4_scan, dim3(BB * HH * GG), dim3(512), 0, stream,
                     qn, kn, v, bt, ATg, Ktg, out);
  hipLaunchKernelGGL(k5_out, dim3(BB * (TT / 32) * HH), dim3(256), 0, stream,
                     graw, onw, Ppt, out);
}